// Round 11
// baseline (407.858 us; speedup 1.0000x reference)
//
#include <hip/hip_runtime.h>
#include <math.h>

#define NLAT 361
#define NLON 720
#define EPSF 1e-7f
#define TWOPI_N 6.283185307179586e+0  // 2*pi; step = TWOPI_N/720

// ---------------------------------------------------------------------------
// Kernel 1: real DFT over longitude, parity-folded output (R7) + quarter-wave
// fold (R10). See R10 notes: k-loop 179 -> 89 iters + tail + center; fold
// variants stored in place keyed on m parity. Output Gp/Gm parity-split
// spectra (center p=180 pre-halved, Gm[180]=0).
// ---------------------------------------------------------------------------
__global__ void dft_kernel(const float* __restrict__ pred,
                           const float* __restrict__ targ,
                           const float* __restrict__ wq,
                           float4* __restrict__ Gp,
                           float4* __restrict__ Gm) {
  const int blk = blockIdx.x;          // 16 * 181 blocks
  const int bc  = blk / 181;
  const int p   = blk - bc * 181;      // 0..180
  const int j0  = p;
  const int j1  = 360 - p;             // p=180: j1==j0 (self-paired)

  const float* fp0 = pred + ((size_t)bc * NLAT + j0) * NLON;
  const float* ft0 = targ + ((size_t)bc * NLAT + j0) * NLON;
  const float* fp1 = pred + ((size_t)bc * NLAT + j1) * NLON;
  const float* ft1 = targ + ((size_t)bc * NLAT + j1) * NLON;

  __shared__ float4 eo[2][360];        // (e_p, o_p, e_t, o_t), n=1..359
  const int tid = threadIdx.x;
  for (int idx = tid; idx < 720; idx += 192) {
    int r = idx / 360, n = idx - 360 * r;
    if (n >= 1) {
      const float* a = r ? fp1 : fp0;
      const float* b = r ? ft1 : ft0;
      float a1 = a[n], a2 = a[NLON - n], b1 = b[n], b2 = b[NLON - n];
      eo[r][n] = make_float4(a1 + a2, a1 - a2, b1 + b2, b1 - b2);
    }
  }
  __syncthreads();

  // quarter-wave fold, in place (each (r,n) pair touched by exactly one thread)
  for (int idx = tid; idx < 2 * 179; idx += 192) {
    int r = idx / 179, n = idx - r * 179 + 1;   // n = 1..179
    float4 A = eo[r][n], B = eo[r][360 - n];
    eo[r][n]       = make_float4(A.x + B.x, A.y - B.y, A.z + B.z, A.w - B.w);
    eo[r][360 - n] = make_float4(A.x - B.x, A.y + B.y, A.z - B.z, A.w + B.w);
  }
  __syncthreads();

  const int m = tid;
  if (m > 180) return;

  float c1, s1, c2, s2, cs, ss;
  {
    float a1 = (float)(TWOPI_N / 720.0 * (double)m);
    float a2 = (float)(TWOPI_N / 720.0 * (double)(2 * m));
    sincosf(a1, &s1, &c1);
    sincosf(a2, &ss, &cs);
    c2 = cs; s2 = ss;
  }

  float CeP0 = 0.f, CoP0 = 0.f, SeP0 = 0.f, SoP0 = 0.f;
  float CeT0 = 0.f, CoT0 = 0.f, SeT0 = 0.f, SoT0 = 0.f;
  float CeP1 = 0.f, CoP1 = 0.f, SeP1 = 0.f, SoP1 = 0.f;
  float CeT1 = 0.f, CoT1 = 0.f, SeT1 = 0.f, SoT1 = 0.f;

  const bool me   = ((m & 1) == 0);
  int i1          = me ? 1 : 359;      // folded index of odd n (2k-1)
  const int dstp  = me ? 2 : -2;
  const int d2    = me ? 1 : -1;       // i2 = i1 + d2 = folded index of 2k

#pragma unroll 2
  for (int k = 1; k <= 89; ++k) {
    float4 u0 = eo[0][i1],      u1 = eo[1][i1];
    float4 v0 = eo[0][i1 + d2], v1 = eo[1][i1 + d2];
    CoP0 += u0.x * c1; SoP0 += u0.y * s1; CoT0 += u0.z * c1; SoT0 += u0.w * s1;
    CoP1 += u1.x * c1; SoP1 += u1.y * s1; CoT1 += u1.z * c1; SoT1 += u1.w * s1;
    CeP0 += v0.x * c2; SeP0 += v0.y * s2; CeT0 += v0.z * c2; SeT0 += v0.w * s2;
    CeP1 += v1.x * c2; SeP1 += v1.y * s2; CeT1 += v1.z * c2; SeT1 += v1.w * s2;
    float nc1 = c1 * cs - s1 * ss, ns1 = s1 * cs + c1 * ss;
    c1 = nc1; s1 = ns1;
    float nc2 = c2 * cs - s2 * ss, ns2 = s2 * cs + c2 * ss;
    c2 = nc2; s2 = ns2;
    i1 += dstp;
  }
  { // tail: odd n = 179; folded idx 179 (even m) / 181 (odd m)
    int it = me ? 179 : 181;
    float4 u0 = eo[0][it], u1 = eo[1][it];
    CoP0 += u0.x * c1; SoP0 += u0.y * s1; CoT0 += u0.z * c1; SoT0 += u0.w * s1;
    CoP1 += u1.x * c1; SoP1 += u1.y * s1; CoT1 += u1.z * c1; SoT1 += u1.w * s1;
  }
  { // center n = 180 (unfolded): cos/sin(m*pi/2) selected by m&1, sign m&2
    float c180 = 0.f, s180 = 0.f;
    if (me) c180 = (m & 2) ? -1.f : 1.f;
    else    s180 = (m & 2) ? -1.f : 1.f;
    float4 z0 = eo[0][180], z1 = eo[1][180];
    CeP0 += z0.x * c180; SeP0 += z0.y * s180;
    CeT0 += z0.z * c180; SeT0 += z0.w * s180;
    CeP1 += z1.x * c180; SeP1 += z1.y * s180;
    CeT1 += z1.z * c180; SeT1 += z1.w * s180;
  }

  const float sgn = me ? 1.f : -1.f;
  const float t0w = (float)(TWOPI_N / 720.0);
  float sc0 = t0w * wq[j0];
  float sc1 = t0w * wq[j1];
  if (p == 180) { sc0 *= 0.5f; sc1 = sc0; }   // self-paired center: pre-halve

  float baseP0 = fp0[0] + sgn * fp0[360], baseT0 = ft0[0] + sgn * ft0[360];
  float baseP1 = fp1[0] + sgn * fp1[360], baseT1 = ft1[0] + sgn * ft1[360];

  // bin m
  {
    float rP0 = (baseP0 + CeP0 + CoP0) * sc0, iP0 = -(SeP0 + SoP0) * sc0;
    float rT0 = (baseT0 + CeT0 + CoT0) * sc0, iT0 = -(SeT0 + SoT0) * sc0;
    float rP1 = (baseP1 + CeP1 + CoP1) * sc1, iP1 = -(SeP1 + SoP1) * sc1;
    float rT1 = (baseT1 + CeT1 + CoT1) * sc1, iT1 = -(SeT1 + SoT1) * sc1;
    size_t o = ((size_t)m * 181 + p) * 16 + bc;
    Gp[o] = make_float4(rP0 + rP1, iP0 + iP1, rT0 + rT1, iT0 + iT1);
    Gm[o] = make_float4(rP0 - rP1, iP0 - iP1, rT0 - rT1, iT0 - iT1);
  }
  // bin 360-m (same m-parity -> same folded arrays valid)
  if (m >= 1 && m <= 179) {
    int m2 = 360 - m;
    float rP0 = (baseP0 + CeP0 - CoP0) * sc0, iP0 = (SeP0 - SoP0) * sc0;
    float rT0 = (baseT0 + CeT0 - CoT0) * sc0, iT0 = (SeT0 - SoT0) * sc0;
    float rP1 = (baseP1 + CeP1 - CoP1) * sc1, iP1 = (SeP1 - SoP1) * sc1;
    float rT1 = (baseT1 + CeT1 - CoT1) * sc1, iT1 = (SeT1 - SoT1) * sc1;
    size_t o = ((size_t)m2 * 181 + p) * 16 + bc;
    Gp[o] = make_float4(rP0 + rP1, iP0 + iP1, rT0 + rT1, iT0 + iT1);
    Gm[o] = make_float4(rP0 - rP1, iP0 - iP1, rT0 - rT1, iT0 - iT1);
  }
}

// ---------------------------------------------------------------------------
// Kernel 2: Legendre contraction + triangular PSD/cross-spectrum.
// R11 restructure (extends R9's proven lever — more FMAs per load, fewer
// loads; R8 showed unroll pragmas can't buy MLP on this compiler):
//   128 thr = 16 bc (lane bits 0..3) x 8 j-lanes (lane bits 4..5 + wave bit);
//   each THREAD owns ALL 16 l-rows (ca[16][4], statically indexed) ->
//   64 FMAs per u0/u1 load pair, u-load redundancy 1x (block load count
//   736 -> 368). Reduction: shfl_xor(16,32) within wave, then one 4KB LDS
//   pass across the two waves. 1 m per block, grid 4416.
// ---------------------------------------------------------------------------
#define ACC16()                                                       \
  do {                                                                \
    ca[0][0] += g0.x * u0.x; ca[0][1] += g0.x * u0.y;                 \
    ca[0][2] += g0.x * u0.z; ca[0][3] += g0.x * u0.w;                 \
    ca[1][0] += g0.y * u1.x; ca[1][1] += g0.y * u1.y;                 \
    ca[1][2] += g0.y * u1.z; ca[1][3] += g0.y * u1.w;                 \
    ca[2][0] += g0.z * u0.x; ca[2][1] += g0.z * u0.y;                 \
    ca[2][2] += g0.z * u0.z; ca[2][3] += g0.z * u0.w;                 \
    ca[3][0] += g0.w * u1.x; ca[3][1] += g0.w * u1.y;                 \
    ca[3][2] += g0.w * u1.z; ca[3][3] += g0.w * u1.w;                 \
    ca[4][0] += g1.x * u0.x; ca[4][1] += g1.x * u0.y;                 \
    ca[4][2] += g1.x * u0.z; ca[4][3] += g1.x * u0.w;                 \
    ca[5][0] += g1.y * u1.x; ca[5][1] += g1.y * u1.y;                 \
    ca[5][2] += g1.y * u1.z; ca[5][3] += g1.y * u1.w;                 \
    ca[6][0] += g1.z * u0.x; ca[6][1] += g1.z * u0.y;                 \
    ca[6][2] += g1.z * u0.z; ca[6][3] += g1.z * u0.w;                 \
    ca[7][0] += g1.w * u1.x; ca[7][1] += g1.w * u1.y;                 \
    ca[7][2] += g1.w * u1.z; ca[7][3] += g1.w * u1.w;                 \
    ca[8][0] += g2.x * u0.x; ca[8][1] += g2.x * u0.y;                 \
    ca[8][2] += g2.x * u0.z; ca[8][3] += g2.x * u0.w;                 \
    ca[9][0] += g2.y * u1.x; ca[9][1] += g2.y * u1.y;                 \
    ca[9][2] += g2.y * u1.z; ca[9][3] += g2.y * u1.w;                 \
    ca[10][0] += g2.z * u0.x; ca[10][1] += g2.z * u0.y;               \
    ca[10][2] += g2.z * u0.z; ca[10][3] += g2.z * u0.w;               \
    ca[11][0] += g2.w * u1.x; ca[11][1] += g2.w * u1.y;               \
    ca[11][2] += g2.w * u1.z; ca[11][3] += g2.w * u1.w;               \
    ca[12][0] += g3.x * u0.x; ca[12][1] += g3.x * u0.y;               \
    ca[12][2] += g3.x * u0.z; ca[12][3] += g3.x * u0.w;               \
    ca[13][0] += g3.y * u1.x; ca[13][1] += g3.y * u1.y;               \
    ca[13][2] += g3.y * u1.z; ca[13][3] += g3.y * u1.w;               \
    ca[14][0] += g3.z * u0.x; ca[14][1] += g3.z * u0.y;               \
    ca[14][2] += g3.z * u0.z; ca[14][3] += g3.z * u0.w;               \
    ca[15][0] += g3.w * u1.x; ca[15][1] += g3.w * u1.y;               \
    ca[15][2] += g3.w * u1.z; ca[15][3] += g3.w * u1.w;               \
  } while (0)

__global__ __launch_bounds__(128, 4)
void leg_kernel(const float* __restrict__ leg,
                const float4* __restrict__ Gp,
                const float4* __restrict__ Gm,
                float4* __restrict__ Spart) {
  int bid = blockIdx.x;
  int lt = 0, acc = 0;
  while (bid >= acc + 16 * (lt + 1)) { acc += 16 * (lt + 1); ++lt; }
  const int l0 = lt * 16;
  const int m  = bid - acc;            // 0 .. 16*(lt+1)-1

  const int tid = threadIdx.x;
  const int bc  = tid & 15;            // 0..15 (coalesced)
  const int jq  = tid >> 4;            // 0..7 (j-lane: lane bits 4..5 + wave)
  const int wv  = tid >> 6;            // wave id

  if (m > 359) {                       // dead tail blocks (lt=22): zero partials
    if (jq == 0) {
      float4* sp = Spart + (size_t)bid * 256;
#pragma unroll
      for (int r = 0; r < 16; ++r)
        sp[bc * 16 + r] = make_float4(0.f, 0.f, 0.f, 0.f);
    }
    return;
  }

  __shared__ float sLg[181][20];       // stride 20 floats (16B-aligned quads)
  __shared__ float4 sRed[16][16];      // cross-wave reduce: [bc][l-row]

  // stage leg[l0..l0+15][m][0..180] transposed (coalesced global read)
  for (int idx = tid; idx < 16 * 181; idx += 128) {
    int lp = idx / 181, j = idx - lp * 181;
    int l = l0 + lp;
    sLg[j][lp] = (l <= 360) ? leg[((size_t)l * NLAT + m) * NLAT + j] : 0.f;
  }
  __syncthreads();

  // row l0+r parity = (l0+m+r)&1. Even r -> u0, odd r -> u1.
  const bool pe = (((l0 + m) & 1) == 0);
  const float4* pu0 = (pe ? Gp : Gm) + (size_t)m * (181 * 16);
  const float4* pu1 = (pe ? Gm : Gp) + (size_t)m * (181 * 16);

  float ca[16][4];
#pragma unroll
  for (int r = 0; r < 16; ++r)
#pragma unroll
    for (int c = 0; c < 4; ++c) ca[r][c] = 0.f;

  for (int j = jq; j <= 180; j += 8) {
    float4 u0 = pu0[j * 16 + bc];
    float4 u1 = pu1[j * 16 + bc];
    const float* lrow = &sLg[j][0];
    float4 g0 = *(const float4*)(lrow);
    float4 g1 = *(const float4*)(lrow + 4);
    float4 g2 = *(const float4*)(lrow + 8);
    float4 g3 = *(const float4*)(lrow + 12);
    ACC16();
  }

  // reduce over lane bits 4..5 (4 j-lanes within each wave)
#pragma unroll
  for (int r = 0; r < 16; ++r)
#pragma unroll
    for (int c = 0; c < 4; ++c) {
      ca[r][c] += __shfl_xor(ca[r][c], 16);
      ca[r][c] += __shfl_xor(ca[r][c], 32);
    }

  // cross-wave reduce via LDS: wave 1 publishes, wave 0 finalizes
  if (wv == 1 && (tid & 0x30) == 0) {
#pragma unroll
    for (int r = 0; r < 16; ++r)
      sRed[bc][r] = make_float4(ca[r][0], ca[r][1], ca[r][2], ca[r][3]);
  }
  __syncthreads();
  if (wv == 0 && (tid & 0x30) == 0) {
    const float ef = (m == 0) ? 1.f : 2.f;
    float4* sp = Spart + (size_t)bid * 256;
#pragma unroll
    for (int r = 0; r < 16; ++r) {
      float4 o = sRed[bc][r];
      float pr = ca[r][0] + o.x, pi = ca[r][1] + o.y;
      float tr = ca[r][2] + o.z, ti = ca[r][3] + o.w;
      sp[bc * 16 + r] =
          make_float4(ef * (pr * pr + pi * pi),
                      ef * (tr * tr + ti * ti),
                      ef * (pr * tr + pi * ti),
                      ef * (pr * ti - pi * tr));
    }
  }
}

// ---------------------------------------------------------------------------
// Kernel 2b: sum per-block partials into S. 92 blocks (4 per l-tile, one
// thread per output element) + 4 independent accumulators (R4). Tile lt has
// nmb = 16*(lt+1) one-m blocks, base = 8*lt*(lt+1).
// ---------------------------------------------------------------------------
__global__ void red_kernel(const float* __restrict__ Spart,
                           float* __restrict__ S) {
  const int b    = blockIdx.x;            // 0..91
  const int lt   = b >> 2;                // 0..22
  const int base = 8 * lt * (lt + 1);     // prefix of 16*(i+1)
  const int nmb  = 16 * (lt + 1);         // m-blocks in this tile
  const int idx  = ((b & 3) << 8) | threadIdx.x;   // 0..1023

  const float* p = Spart + (size_t)base * 1024 + idx;
  float s0 = 0.f, s1 = 0.f, s2 = 0.f, s3 = 0.f;
  for (int mb = 0; mb < nmb; mb += 4) {
    s0 += p[(size_t)(mb + 0) * 1024];
    s1 += p[(size_t)(mb + 1) * 1024];
    s2 += p[(size_t)(mb + 2) * 1024];
    s3 += p[(size_t)(mb + 3) * 1024];
  }
  float s = (s0 + s1) + (s2 + s3);
  int bc = idx >> 6, lrow = (idx >> 2) & 15, c = idx & 3;
  int l = lt * 16 + lrow;
  if (l < 360) S[((size_t)bc * 360 + l) * 4 + c] = s;
}

// ---------------------------------------------------------------------------
// Kernel 3: final loss epilogue + reduction. One block.
// ---------------------------------------------------------------------------
__global__ void loss_kernel(const float* __restrict__ S,
                            const float* __restrict__ wts,
                            float* __restrict__ out) {
  const int tid = threadIdx.x;
  float acc = 0.f;
  for (int i = tid; i < 16 * 360; i += 256) {
    int bc = i / 360;
    const float* sp = S + (size_t)i * 4;
    float pp = sp[0] + EPSF;
    float tp = sp[1] + EPSF;
    float sr = sp[2], si = sp[3];
    float mag   = sqrtf(sr * sr + si * si);
    float denom = sqrtf(pp * tp + EPSF);
    float coh   = mag / (denom + EPSF);
    coh = fminf(fmaxf(coh, 0.f), 1.f);
    float sqp = sqrtf(pp), sqt = sqrtf(tp);
    float amp = (sqp - sqt) * (sqp - sqt);
    float dec = 2.f * fmaxf(pp, tp) * (1.f - coh);
    acc += (amp + dec) * wts[bc & 7];
  }
  __shared__ float red[4];
#pragma unroll
  for (int off = 32; off > 0; off >>= 1) acc += __shfl_xor(acc, off, 64);
  if ((tid & 63) == 0) red[tid >> 6] = acc;
  __syncthreads();
  if (tid == 0) {
    float loss = (red[0] + red[1] + red[2] + red[3]) / (360.f * 16.f);
    out[0] = isnan(loss) ? 1e6f : loss;
  }
}

// ---------------------------------------------------------------------------
extern "C" void kernel_launch(void* const* d_in, const int* in_sizes, int n_in,
                              void* d_out, int out_size, void* d_ws, size_t ws_size,
                              hipStream_t stream) {
  const float* pred = (const float*)d_in[0];   // [2,8,361,720]
  const float* targ = (const float*)d_in[1];   // [2,8,361,720]
  const float* wts  = (const float*)d_in[2];   // [8]
  const float* leg  = (const float*)d_in[3];   // [361,361,361]
  const float* wq   = (const float*)d_in[4];   // [361]
  float* out = (float*)d_out;

  float4* Gp    = (float4*)d_ws;                              // [360][181][16] float4
  float4* Gm    = Gp + (size_t)360 * 181 * 16;                // [360][181][16] float4
  float*  S     = (float*)(Gm + (size_t)360 * 181 * 16);      // [16][360][4]
  float*  Spart = S + (size_t)16 * 360 * 4;                   // [4416][1024]

  dft_kernel<<<16 * 181, 192, 0, stream>>>(pred, targ, wq, Gp, Gm);

  // 4416 = sum over 23 l-tiles of 16*(lt+1) one-m blocks
  leg_kernel<<<4416, 128, 0, stream>>>(leg, Gp, Gm, (float4*)Spart);

  red_kernel<<<92, 256, 0, stream>>>(Spart, S);

  loss_kernel<<<1, 256, 0, stream>>>(S, wts, out);
}

// Round 12
// 399.555 us; speedup vs baseline: 1.0208x; 1.0208x over previous
//
#include <hip/hip_runtime.h>
#include <math.h>

#define NLAT 361
#define NLON 720
#define EPSF 1e-7f
#define TWOPI_N 6.283185307179586e+0  // 2*pi; step = TWOPI_N/720

// ---------------------------------------------------------------------------
// Kernel 1: real DFT over longitude, parity-folded output (R7) + quarter-wave
// fold (R10). k-loop 179 -> 89 iters + tail + center; fold variants stored in
// place keyed on m parity. Output Gp/Gm parity-split spectra (center p=180
// pre-halved, Gm[180]=0).
// ---------------------------------------------------------------------------
__global__ void dft_kernel(const float* __restrict__ pred,
                           const float* __restrict__ targ,
                           const float* __restrict__ wq,
                           float4* __restrict__ Gp,
                           float4* __restrict__ Gm) {
  const int blk = blockIdx.x;          // 16 * 181 blocks
  const int bc  = blk / 181;
  const int p   = blk - bc * 181;      // 0..180
  const int j0  = p;
  const int j1  = 360 - p;             // p=180: j1==j0 (self-paired)

  const float* fp0 = pred + ((size_t)bc * NLAT + j0) * NLON;
  const float* ft0 = targ + ((size_t)bc * NLAT + j0) * NLON;
  const float* fp1 = pred + ((size_t)bc * NLAT + j1) * NLON;
  const float* ft1 = targ + ((size_t)bc * NLAT + j1) * NLON;

  __shared__ float4 eo[2][360];        // (e_p, o_p, e_t, o_t), n=1..359
  const int tid = threadIdx.x;
  for (int idx = tid; idx < 720; idx += 192) {
    int r = idx / 360, n = idx - 360 * r;
    if (n >= 1) {
      const float* a = r ? fp1 : fp0;
      const float* b = r ? ft1 : ft0;
      float a1 = a[n], a2 = a[NLON - n], b1 = b[n], b2 = b[NLON - n];
      eo[r][n] = make_float4(a1 + a2, a1 - a2, b1 + b2, b1 - b2);
    }
  }
  __syncthreads();

  // quarter-wave fold, in place (each (r,n) pair touched by exactly one thread)
  for (int idx = tid; idx < 2 * 179; idx += 192) {
    int r = idx / 179, n = idx - r * 179 + 1;   // n = 1..179
    float4 A = eo[r][n], B = eo[r][360 - n];
    eo[r][n]       = make_float4(A.x + B.x, A.y - B.y, A.z + B.z, A.w - B.w);
    eo[r][360 - n] = make_float4(A.x - B.x, A.y + B.y, A.z - B.z, A.w + B.w);
  }
  __syncthreads();

  const int m = tid;
  if (m > 180) return;

  float c1, s1, c2, s2, cs, ss;
  {
    float a1 = (float)(TWOPI_N / 720.0 * (double)m);
    float a2 = (float)(TWOPI_N / 720.0 * (double)(2 * m));
    sincosf(a1, &s1, &c1);
    sincosf(a2, &ss, &cs);
    c2 = cs; s2 = ss;
  }

  float CeP0 = 0.f, CoP0 = 0.f, SeP0 = 0.f, SoP0 = 0.f;
  float CeT0 = 0.f, CoT0 = 0.f, SeT0 = 0.f, SoT0 = 0.f;
  float CeP1 = 0.f, CoP1 = 0.f, SeP1 = 0.f, SoP1 = 0.f;
  float CeT1 = 0.f, CoT1 = 0.f, SeT1 = 0.f, SoT1 = 0.f;

  const bool me   = ((m & 1) == 0);
  int i1          = me ? 1 : 359;      // folded index of odd n (2k-1)
  const int dstp  = me ? 2 : -2;
  const int d2    = me ? 1 : -1;       // i2 = i1 + d2 = folded index of 2k

#pragma unroll 2
  for (int k = 1; k <= 89; ++k) {
    float4 u0 = eo[0][i1],      u1 = eo[1][i1];
    float4 v0 = eo[0][i1 + d2], v1 = eo[1][i1 + d2];
    CoP0 += u0.x * c1; SoP0 += u0.y * s1; CoT0 += u0.z * c1; SoT0 += u0.w * s1;
    CoP1 += u1.x * c1; SoP1 += u1.y * s1; CoT1 += u1.z * c1; SoT1 += u1.w * s1;
    CeP0 += v0.x * c2; SeP0 += v0.y * s2; CeT0 += v0.z * c2; SeT0 += v0.w * s2;
    CeP1 += v1.x * c2; SeP1 += v1.y * s2; CeT1 += v1.z * c2; SeT1 += v1.w * s2;
    float nc1 = c1 * cs - s1 * ss, ns1 = s1 * cs + c1 * ss;
    c1 = nc1; s1 = ns1;
    float nc2 = c2 * cs - s2 * ss, ns2 = s2 * cs + c2 * ss;
    c2 = nc2; s2 = ns2;
    i1 += dstp;
  }
  { // tail: odd n = 179; folded idx 179 (even m) / 181 (odd m)
    int it = me ? 179 : 181;
    float4 u0 = eo[0][it], u1 = eo[1][it];
    CoP0 += u0.x * c1; SoP0 += u0.y * s1; CoT0 += u0.z * c1; SoT0 += u0.w * s1;
    CoP1 += u1.x * c1; SoP1 += u1.y * s1; CoT1 += u1.z * c1; SoT1 += u1.w * s1;
  }
  { // center n = 180 (unfolded): cos/sin(m*pi/2) selected by m&1, sign m&2
    float c180 = 0.f, s180 = 0.f;
    if (me) c180 = (m & 2) ? -1.f : 1.f;
    else    s180 = (m & 2) ? -1.f : 1.f;
    float4 z0 = eo[0][180], z1 = eo[1][180];
    CeP0 += z0.x * c180; SeP0 += z0.y * s180;
    CeT0 += z0.z * c180; SeT0 += z0.w * s180;
    CeP1 += z1.x * c180; SeP1 += z1.y * s180;
    CeT1 += z1.z * c180; SeT1 += z1.w * s180;
  }

  const float sgn = me ? 1.f : -1.f;
  const float t0w = (float)(TWOPI_N / 720.0);
  float sc0 = t0w * wq[j0];
  float sc1 = t0w * wq[j1];
  if (p == 180) { sc0 *= 0.5f; sc1 = sc0; }   // self-paired center: pre-halve

  float baseP0 = fp0[0] + sgn * fp0[360], baseT0 = ft0[0] + sgn * ft0[360];
  float baseP1 = fp1[0] + sgn * fp1[360], baseT1 = ft1[0] + sgn * ft1[360];

  // bin m
  {
    float rP0 = (baseP0 + CeP0 + CoP0) * sc0, iP0 = -(SeP0 + SoP0) * sc0;
    float rT0 = (baseT0 + CeT0 + CoT0) * sc0, iT0 = -(SeT0 + SoT0) * sc0;
    float rP1 = (baseP1 + CeP1 + CoP1) * sc1, iP1 = -(SeP1 + SoP1) * sc1;
    float rT1 = (baseT1 + CeT1 + CoT1) * sc1, iT1 = -(SeT1 + SoT1) * sc1;
    size_t o = ((size_t)m * 181 + p) * 16 + bc;
    Gp[o] = make_float4(rP0 + rP1, iP0 + iP1, rT0 + rT1, iT0 + iT1);
    Gm[o] = make_float4(rP0 - rP1, iP0 - iP1, rT0 - rT1, iT0 - iT1);
  }
  // bin 360-m (same m-parity -> same folded arrays valid)
  if (m >= 1 && m <= 179) {
    int m2 = 360 - m;
    float rP0 = (baseP0 + CeP0 - CoP0) * sc0, iP0 = (SeP0 - SoP0) * sc0;
    float rT0 = (baseT0 + CeT0 - CoT0) * sc0, iT0 = (SeT0 - SoT0) * sc0;
    float rP1 = (baseP1 + CeP1 - CoP1) * sc1, iP1 = (SeP1 - SoP1) * sc1;
    float rT1 = (baseT1 + CeT1 - CoT1) * sc1, iT1 = (SeT1 - SoT1) * sc1;
    size_t o = ((size_t)m2 * 181 + p) * 16 + bc;
    Gp[o] = make_float4(rP0 + rP1, iP0 + iP1, rT0 + rT1, iT0 + iT1);
    Gm[o] = make_float4(rP0 - rP1, iP0 - iP1, rT0 - rT1, iT0 - iT1);
  }
}

// ---------------------------------------------------------------------------
// Kernel 2: Legendre contraction + triangular PSD/cross-spectrum.
// Inner structure = R9 proven local optimum (R11's 16-rows/thread regressed):
//   128 thr = 16 bc x 4 jl x 2 lg(wave); 8 l-rows/thread -> 32 FMAs per
//   u0/u1 load pair, 2x load redundancy.
// R12 change: RECTANGULAR grid [23 lt][360 m], bid = lt*360 + m. Since
// 360 % 8 == 0, bid % 8 == m % 8 -> all blocks sharing m land on the SAME
// XCD (round-robin heuristic). Per-XCD G working set = 45 m x 92.7 KB
// ~= 4.2 MB ~= one L2: the 12x G reuse (409 MB reads vs 33 MB array)
// becomes L2-hits instead of L3 round-trips. Upper-triangle blocks
// (m > 16*lt+15) exit immediately; red_kernel never reads their slots.
// ---------------------------------------------------------------------------
__global__ __launch_bounds__(128, 4)
void leg_kernel(const float* __restrict__ leg,
                const float4* __restrict__ Gp,
                const float4* __restrict__ Gm,
                float4* __restrict__ Spart) {
  const int bid = blockIdx.x;          // [23][360]
  const int lt  = bid / 360;
  const int m   = bid - lt * 360;      // 0..359
  const int l0  = lt * 16;

  if (m > 16 * lt + 15) return;        // dead upper-triangle block

  const int tid = threadIdx.x;
  const int bc  = tid & 15;            // 0..15 (coalesced)
  const int jl  = (tid >> 4) & 3;      // 0..3
  const int lg  = tid >> 6;            // 0..1 (wave id; rows lg*8 .. lg*8+7)

  __shared__ float sLg[181][20];       // stride 20 floats (16B-aligned quads)
  // stage leg[l0..l0+15][m][0..180] transposed (coalesced global read)
  for (int idx = tid; idx < 16 * 181; idx += 128) {
    int lp = idx / 181, j = idx - lp * 181;
    int l = l0 + lp;
    sLg[j][lp] = (l <= 360) ? leg[((size_t)l * NLAT + m) * NLAT + j] : 0.f;
  }
  __syncthreads();

  // row l0+lg*8+r parity = (l0+m+r)&1 (lg*8 even). Even r -> u0, odd -> u1.
  const bool pe = (((l0 + m) & 1) == 0);
  const float4* pu0 = (pe ? Gp : Gm) + (size_t)m * (181 * 16);
  const float4* pu1 = (pe ? Gm : Gp) + (size_t)m * (181 * 16);

  float ca[8][4];
#pragma unroll
  for (int r = 0; r < 8; ++r)
#pragma unroll
    for (int c = 0; c < 4; ++c) ca[r][c] = 0.f;

#pragma unroll 2
  for (int j = jl; j <= 180; j += 4) {
    float4 u0 = pu0[j * 16 + bc];
    float4 u1 = pu1[j * 16 + bc];
    const float* lrow = &sLg[j][lg * 8];
    float4 g0 = *(const float4*)lrow;
    float4 g1 = *(const float4*)(lrow + 4);
    ca[0][0] += g0.x * u0.x; ca[0][1] += g0.x * u0.y;
    ca[0][2] += g0.x * u0.z; ca[0][3] += g0.x * u0.w;
    ca[1][0] += g0.y * u1.x; ca[1][1] += g0.y * u1.y;
    ca[1][2] += g0.y * u1.z; ca[1][3] += g0.y * u1.w;
    ca[2][0] += g0.z * u0.x; ca[2][1] += g0.z * u0.y;
    ca[2][2] += g0.z * u0.z; ca[2][3] += g0.z * u0.w;
    ca[3][0] += g0.w * u1.x; ca[3][1] += g0.w * u1.y;
    ca[3][2] += g0.w * u1.z; ca[3][3] += g0.w * u1.w;
    ca[4][0] += g1.x * u0.x; ca[4][1] += g1.x * u0.y;
    ca[4][2] += g1.x * u0.z; ca[4][3] += g1.x * u0.w;
    ca[5][0] += g1.y * u1.x; ca[5][1] += g1.y * u1.y;
    ca[5][2] += g1.y * u1.z; ca[5][3] += g1.y * u1.w;
    ca[6][0] += g1.z * u0.x; ca[6][1] += g1.z * u0.y;
    ca[6][2] += g1.z * u0.z; ca[6][3] += g1.z * u0.w;
    ca[7][0] += g1.w * u1.x; ca[7][1] += g1.w * u1.y;
    ca[7][2] += g1.w * u1.z; ca[7][3] += g1.w * u1.w;
  }

  // reduce across the 4 j-lanes (lane bits 4..5)
#pragma unroll
  for (int r = 0; r < 8; ++r)
#pragma unroll
    for (int c = 0; c < 4; ++c) {
      ca[r][c] += __shfl_xor(ca[r][c], 16);
      ca[r][c] += __shfl_xor(ca[r][c], 32);
    }

  if (jl == 0) {
    const float ef = (m == 0) ? 1.f : 2.f;
    float4* sp = Spart + (size_t)bid * 256;
#pragma unroll
    for (int r = 0; r < 8; ++r) {
      float pr = ca[r][0], pi = ca[r][1], tr = ca[r][2], ti = ca[r][3];
      sp[bc * 16 + lg * 8 + r] =
          make_float4(ef * (pr * pr + pi * pi),
                      ef * (tr * tr + ti * ti),
                      ef * (pr * tr + pi * ti),
                      ef * (pr * ti - pi * tr));
    }
  }
}

// ---------------------------------------------------------------------------
// Kernel 2b: sum per-block partials into S. 92 blocks (4 per l-tile, one
// thread per output element) + 4 independent accumulators (R4). Tile lt's
// valid m-range is 0..min(16*lt+15, 359): nmb = min(16*(lt+1), 360), always
// divisible by 4; base = lt*360 (rectangular Spart layout, R12).
// ---------------------------------------------------------------------------
__global__ void red_kernel(const float* __restrict__ Spart,
                           float* __restrict__ S) {
  const int b    = blockIdx.x;            // 0..91
  const int lt   = b >> 2;                // 0..22
  const int base = lt * 360;
  const int nmb  = (16 * (lt + 1) < 360) ? 16 * (lt + 1) : 360;
  const int idx  = ((b & 3) << 8) | threadIdx.x;   // 0..1023

  const float* p = Spart + (size_t)base * 1024 + idx;
  float s0 = 0.f, s1 = 0.f, s2 = 0.f, s3 = 0.f;
  for (int mb = 0; mb < nmb; mb += 4) {
    s0 += p[(size_t)(mb + 0) * 1024];
    s1 += p[(size_t)(mb + 1) * 1024];
    s2 += p[(size_t)(mb + 2) * 1024];
    s3 += p[(size_t)(mb + 3) * 1024];
  }
  float s = (s0 + s1) + (s2 + s3);
  int bc = idx >> 6, lrow = (idx >> 2) & 15, c = idx & 3;
  int l = lt * 16 + lrow;
  if (l < 360) S[((size_t)bc * 360 + l) * 4 + c] = s;
}

// ---------------------------------------------------------------------------
// Kernel 3: final loss epilogue + reduction. One block.
// ---------------------------------------------------------------------------
__global__ void loss_kernel(const float* __restrict__ S,
                            const float* __restrict__ wts,
                            float* __restrict__ out) {
  const int tid = threadIdx.x;
  float acc = 0.f;
  for (int i = tid; i < 16 * 360; i += 256) {
    int bc = i / 360;
    const float* sp = S + (size_t)i * 4;
    float pp = sp[0] + EPSF;
    float tp = sp[1] + EPSF;
    float sr = sp[2], si = sp[3];
    float mag   = sqrtf(sr * sr + si * si);
    float denom = sqrtf(pp * tp + EPSF);
    float coh   = mag / (denom + EPSF);
    coh = fminf(fmaxf(coh, 0.f), 1.f);
    float sqp = sqrtf(pp), sqt = sqrtf(tp);
    float amp = (sqp - sqt) * (sqp - sqt);
    float dec = 2.f * fmaxf(pp, tp) * (1.f - coh);
    acc += (amp + dec) * wts[bc & 7];
  }
  __shared__ float red[4];
#pragma unroll
  for (int off = 32; off > 0; off >>= 1) acc += __shfl_xor(acc, off, 64);
  if ((tid & 63) == 0) red[tid >> 6] = acc;
  __syncthreads();
  if (tid == 0) {
    float loss = (red[0] + red[1] + red[2] + red[3]) / (360.f * 16.f);
    out[0] = isnan(loss) ? 1e6f : loss;
  }
}

// ---------------------------------------------------------------------------
extern "C" void kernel_launch(void* const* d_in, const int* in_sizes, int n_in,
                              void* d_out, int out_size, void* d_ws, size_t ws_size,
                              hipStream_t stream) {
  const float* pred = (const float*)d_in[0];   // [2,8,361,720]
  const float* targ = (const float*)d_in[1];   // [2,8,361,720]
  const float* wts  = (const float*)d_in[2];   // [8]
  const float* leg  = (const float*)d_in[3];   // [361,361,361]
  const float* wq   = (const float*)d_in[4];   // [361]
  float* out = (float*)d_out;

  float4* Gp    = (float4*)d_ws;                              // [360][181][16] float4
  float4* Gm    = Gp + (size_t)360 * 181 * 16;                // [360][181][16] float4
  float*  S     = (float*)(Gm + (size_t)360 * 181 * 16);      // [16][360][4]
  float*  Spart = S + (size_t)16 * 360 * 4;                   // [23*360][1024]

  dft_kernel<<<16 * 181, 192, 0, stream>>>(pred, targ, wq, Gp, Gm);

  // rectangular grid [23 lt][360 m]; bid%8 == m%8 -> same-m blocks share XCD
  leg_kernel<<<23 * 360, 128, 0, stream>>>(leg, Gp, Gm, (float4*)Spart);

  red_kernel<<<92, 256, 0, stream>>>(Spart, S);

  loss_kernel<<<1, 256, 0, stream>>>(S, wts, out);
}